// Round 1
// baseline (475.505 us; speedup 1.0000x reference)
//
#include <hip/hip_runtime.h>
#include <math.h>

// ---- problem constants ----
constexpr int Bc  = 4;
constexpr int Sc  = 2048;
constexpr int DIN = 512;   // also d_model
constexpr int Hc  = 8;
constexpr int DKc = 64;

typedef __attribute__((ext_vector_type(8))) short s16x8;   // 8 bf16 (4 VGPRs)
typedef __attribute__((ext_vector_type(4))) float f32x4;   // 4 fp32 acc

__device__ __forceinline__ unsigned short f2bf(float f) {
    union { float f; unsigned int u; } v; v.f = f;
    unsigned int u = v.u;
    unsigned int r = (u + 0x7FFFu + ((u >> 16) & 1u)) >> 16;
    return (unsigned short)r;
}

// =====================================================================
// Kernel 1: QKV projections. C = A(fp32)[8192x512] @ W(fp32)[512x512] + b
// Output bf16 in [B,H,S,DK] layout. grid = (128, 8, 3), block = 256.
// =====================================================================
__global__ __launch_bounds__(256) void qkv_proj(
    const float* __restrict__ qin, const float* __restrict__ kin, const float* __restrict__ vin,
    const float* __restrict__ Wq,  const float* __restrict__ Wk,  const float* __restrict__ Wv,
    const float* __restrict__ bq,  const float* __restrict__ bk,  const float* __restrict__ bv,
    unsigned short* __restrict__ Qp, unsigned short* __restrict__ Kp, unsigned short* __restrict__ Vp)
{
    const int z = blockIdx.z;
    const float* A    = (z == 0) ? qin : (z == 1) ? kin : vin;
    const float* W    = (z == 0) ? Wq  : (z == 1) ? Wk  : Wv;
    const float* bias = (z == 0) ? bq  : (z == 1) ? bk  : bv;
    unsigned short* Out = (z == 0) ? Qp : (z == 1) ? Kp : Vp;

    __shared__ unsigned short As[64][32];   // A tile, [row][k]
    __shared__ unsigned short Bs[64][40];   // W^T tile, [n][k], padded (stride 80B, 16B-aligned)

    const int tid  = threadIdx.x;
    const int lane = tid & 63;
    const int w    = tid >> 6;
    const int l16  = lane & 15;
    const int quad = lane >> 4;
    const int bm   = blockIdx.x;
    const int bn   = blockIdx.y;

    f32x4 acc[4] = {{0,0,0,0},{0,0,0,0},{0,0,0,0},{0,0,0,0}};

    for (int kt = 0; kt < 16; ++kt) {
        const int k0 = kt * 32;
        // stage A tile (64 rows x 32 k), fp32 -> bf16
        {
            const int row = tid >> 3;
            const int col = (tid & 7) * 4;
#pragma unroll
            for (int rr = 0; rr < 2; ++rr) {
                const float4 a4 = *(const float4*)&A[(size_t)(bm * 64 + row + rr * 32) * 512 + k0 + col];
                ushort4 b4;
                b4.x = f2bf(a4.x); b4.y = f2bf(a4.y); b4.z = f2bf(a4.z); b4.w = f2bf(a4.w);
                *(ushort4*)&As[row + rr * 32][col] = b4;
            }
        }
        // stage W tile transposed (32 k x 64 n -> Bs[n][k])
        {
            const int kk = tid >> 4;
            const int n4 = (tid & 15) * 4;
#pragma unroll
            for (int rr = 0; rr < 2; ++rr) {
                const float4 w4 = *(const float4*)&W[(size_t)(k0 + kk + rr * 16) * 512 + bn * 64 + n4];
                Bs[n4 + 0][kk + rr * 16] = f2bf(w4.x);
                Bs[n4 + 1][kk + rr * 16] = f2bf(w4.y);
                Bs[n4 + 2][kk + rr * 16] = f2bf(w4.z);
                Bs[n4 + 3][kk + rr * 16] = f2bf(w4.w);
            }
        }
        __syncthreads();
        const s16x8 af = *(const s16x8*)&As[w * 16 + l16][quad * 8];
#pragma unroll
        for (int nt = 0; nt < 4; ++nt) {
            const s16x8 bf = *(const s16x8*)&Bs[nt * 16 + l16][quad * 8];
            acc[nt] = __builtin_amdgcn_mfma_f32_16x16x32_bf16(af, bf, acc[nt], 0, 0, 0);
        }
        __syncthreads();
    }
    // epilogue: bias add, write bf16 [B,H,S,DK]
#pragma unroll
    for (int nt = 0; nt < 4; ++nt) {
        const int gn = bn * 64 + nt * 16 + l16;
        const float bval = bias[gn];
        const int h  = gn >> 6;
        const int dk = gn & 63;
#pragma unroll
        for (int r = 0; r < 4; ++r) {
            const int gm = bm * 64 + w * 16 + quad * 4 + r;
            const int bb = gm >> 11;
            const int s  = gm & 2047;
            Out[(((size_t)bb * Hc + h) * Sc + s) * 64 + dk] = f2bf(acc[nt][r] + bval);
        }
    }
}

// =====================================================================
// Kernel 2: flash-style attention. grid = (H, S/64, B), block = 256.
// Per block: 64 q-rows for one (b,h); stream 32 k-tiles of 64.
// =====================================================================
__global__ __launch_bounds__(256) void attn_kernel(
    const unsigned short* __restrict__ Qp, const unsigned short* __restrict__ Kp,
    const unsigned short* __restrict__ Vp, const float* __restrict__ mask,
    unsigned short* __restrict__ Ap)
{
    __shared__ unsigned short Qs[64][64];   // [q][dk]
    __shared__ unsigned short Ks[64][64];   // [sk][dk]  (= B^T for QK^T)
    __shared__ unsigned short Vt[64][72];   // [dk][sk]  (= B^T for PV), padded
    __shared__ unsigned short Ps[64][72];   // [q][sk]   P in A-layout, padded

    const int tid  = threadIdx.x;
    const int lane = tid & 63;
    const int w    = tid >> 6;
    const int l16  = lane & 15;
    const int quad = lane >> 4;
    const int h  = blockIdx.x;
    const int qt = blockIdx.y;
    const int b  = blockIdx.z;
    const int q0 = qt * 64;

    const unsigned short* Qb = Qp + (((size_t)b * Hc + h) * Sc + q0) * 64;
    const unsigned short* Kb = Kp + (((size_t)b * Hc + h) * Sc) * 64;
    const unsigned short* Vb = Vp + (((size_t)b * Hc + h) * Sc) * 64;

    // load Q tile once
    {
        const int row = tid >> 2;
        const int c   = (tid & 3) * 16;
        *(uint4*)&Qs[row][c]     = *(const uint4*)&Qb[(size_t)row * 64 + c];
        *(uint4*)&Qs[row][c + 8] = *(const uint4*)&Qb[(size_t)row * 64 + c + 8];
    }
    __syncthreads();
    const s16x8 qf0 = *(const s16x8*)&Qs[w * 16 + l16][quad * 8];
    const s16x8 qf1 = *(const s16x8*)&Qs[w * 16 + l16][32 + quad * 8];

    float m_run[4] = {-1e30f, -1e30f, -1e30f, -1e30f};
    float l_run[4] = {0.f, 0.f, 0.f, 0.f};
    f32x4 o_acc[4] = {{0,0,0,0},{0,0,0,0},{0,0,0,0},{0,0,0,0}};

    const float* mb = mask + (size_t)b * Sc * Sc;

    for (int kt = 0; kt < 32; ++kt) {
        const int kbase = kt * 64;
        // stage K tile (as-is) and V tile (transposed)
        {
            const int row = tid >> 2;
            const int c   = (tid & 3) * 16;
            *(uint4*)&Ks[row][c]     = *(const uint4*)&Kb[(size_t)(kbase + row) * 64 + c];
            *(uint4*)&Ks[row][c + 8] = *(const uint4*)&Kb[(size_t)(kbase + row) * 64 + c + 8];
        }
        {
#pragma unroll
            for (int p = 0; p < 8; ++p) {
                const int r   = p * 8 + (tid >> 5);
                const int dkp = tid & 31;
                const unsigned int vv = *(const unsigned int*)&Vb[(size_t)(kbase + r) * 64 + dkp * 2];
                Vt[dkp * 2][r]     = (unsigned short)(vv & 0xffffu);
                Vt[dkp * 2 + 1][r] = (unsigned short)(vv >> 16);
            }
        }
        __syncthreads();
        // scores: S = Q K^T  (wave w: q rows 16w..16w+15, all 64 sk cols)
        f32x4 sc[4] = {{0,0,0,0},{0,0,0,0},{0,0,0,0},{0,0,0,0}};
#pragma unroll
        for (int nt = 0; nt < 4; ++nt) {
            const s16x8 kf0 = *(const s16x8*)&Ks[nt * 16 + l16][quad * 8];
            const s16x8 kf1 = *(const s16x8*)&Ks[nt * 16 + l16][32 + quad * 8];
            sc[nt] = __builtin_amdgcn_mfma_f32_16x16x32_bf16(qf0, kf0, sc[nt], 0, 0, 0);
            sc[nt] = __builtin_amdgcn_mfma_f32_16x16x32_bf16(qf1, kf1, sc[nt], 0, 0, 0);
        }
        // mask * threshold + online softmax (per-row state replicated in 16-lane groups)
#pragma unroll
        for (int r = 0; r < 4; ++r) {
            const int gq = q0 + w * 16 + quad * 4 + r;
            const float* mr = mb + (size_t)gq * Sc + kbase;
            float sv[4];
            float mx = -1e30f;
#pragma unroll
            for (int nt = 0; nt < 4; ++nt) {
                float vsc = sc[nt][r] * 0.125f * mr[nt * 16 + l16];
                vsc = (vsc > 0.0f) ? vsc : -10000.0f;
                sv[nt] = vsc;
                mx = fmaxf(mx, vsc);
            }
#pragma unroll
            for (int off = 1; off < 16; off <<= 1) mx = fmaxf(mx, __shfl_xor(mx, off));
            const float mnew  = fmaxf(m_run[r], mx);
            const float alpha = __expf(m_run[r] - mnew);
            m_run[r] = mnew;
            float rs = 0.0f;
#pragma unroll
            for (int nt = 0; nt < 4; ++nt) {
                const float p = __expf(sv[nt] - mnew);
                rs += p;
                Ps[w * 16 + quad * 4 + r][nt * 16 + l16] = f2bf(p);
            }
#pragma unroll
            for (int off = 1; off < 16; off <<= 1) rs += __shfl_xor(rs, off);
            l_run[r] = l_run[r] * alpha + rs;
#pragma unroll
            for (int nt = 0; nt < 4; ++nt) o_acc[nt][r] *= alpha;
        }
        // PV: O += P @ V   (Ps rows 16w..16w+15 are wave-private; no barrier needed)
#pragma unroll
        for (int nt = 0; nt < 4; ++nt) {
#pragma unroll
            for (int kk = 0; kk < 2; ++kk) {
                const s16x8 pf = *(const s16x8*)&Ps[w * 16 + l16][kk * 32 + quad * 8];
                const s16x8 vf = *(const s16x8*)&Vt[nt * 16 + l16][kk * 32 + quad * 8];
                o_acc[nt] = __builtin_amdgcn_mfma_f32_16x16x32_bf16(pf, vf, o_acc[nt], 0, 0, 0);
            }
        }
        __syncthreads();
    }
    // epilogue: O / l, write bf16 [B,S,H*DK]
#pragma unroll
    for (int r = 0; r < 4; ++r) {
        const int gq = q0 + w * 16 + quad * 4 + r;
        const float inv_l = 1.0f / l_run[r];
#pragma unroll
        for (int nt = 0; nt < 4; ++nt) {
            Ap[((size_t)b * Sc + gq) * 512 + h * 64 + nt * 16 + l16] = f2bf(o_acc[nt][r] * inv_l);
        }
    }
}

// =====================================================================
// Kernel 3: output projection. C = A(bf16)[8192x512] @ Wo + bo -> fp32 ws
// grid = (128, 8), block = 256.
// =====================================================================
__global__ __launch_bounds__(256) void out_proj(
    const unsigned short* __restrict__ Apm, const float* __restrict__ Wo,
    const float* __restrict__ bo, float* __restrict__ O2)
{
    __shared__ unsigned short As[64][32];
    __shared__ unsigned short Bs[64][40];

    const int tid  = threadIdx.x;
    const int lane = tid & 63;
    const int w    = tid >> 6;
    const int l16  = lane & 15;
    const int quad = lane >> 4;
    const int bm   = blockIdx.x;
    const int bn   = blockIdx.y;

    f32x4 acc[4] = {{0,0,0,0},{0,0,0,0},{0,0,0,0},{0,0,0,0}};

    for (int kt = 0; kt < 16; ++kt) {
        const int k0 = kt * 32;
        // stage A tile (already bf16)
        {
            const int row = tid >> 2;
            const int c   = (tid & 3) * 8;
            *(uint4*)&As[row][c] = *(const uint4*)&Apm[(size_t)(bm * 64 + row) * 512 + k0 + c];
        }
        // stage Wo tile transposed
        {
            const int kk = tid >> 4;
            const int n4 = (tid & 15) * 4;
#pragma unroll
            for (int rr = 0; rr < 2; ++rr) {
                const float4 w4 = *(const float4*)&Wo[(size_t)(k0 + kk + rr * 16) * 512 + bn * 64 + n4];
                Bs[n4 + 0][kk + rr * 16] = f2bf(w4.x);
                Bs[n4 + 1][kk + rr * 16] = f2bf(w4.y);
                Bs[n4 + 2][kk + rr * 16] = f2bf(w4.z);
                Bs[n4 + 3][kk + rr * 16] = f2bf(w4.w);
            }
        }
        __syncthreads();
        const s16x8 af = *(const s16x8*)&As[w * 16 + l16][quad * 8];
#pragma unroll
        for (int nt = 0; nt < 4; ++nt) {
            const s16x8 bf = *(const s16x8*)&Bs[nt * 16 + l16][quad * 8];
            acc[nt] = __builtin_amdgcn_mfma_f32_16x16x32_bf16(af, bf, acc[nt], 0, 0, 0);
        }
        __syncthreads();
    }
#pragma unroll
    for (int nt = 0; nt < 4; ++nt) {
        const int gn = bn * 64 + nt * 16 + l16;
        const float bval = bo[gn];
#pragma unroll
        for (int r = 0; r < 4; ++r) {
            const int gm = bm * 64 + w * 16 + quad * 4 + r;
            O2[(size_t)gm * 512 + gn] = acc[nt][r] + bval;
        }
    }
}

// =====================================================================
// Kernel 4: residual + LayerNorm. grid = 8192 rows, block = 256.
// =====================================================================
__global__ __launch_bounds__(256) void ln_kernel(
    const float* __restrict__ q, const float* __restrict__ O2,
    const float* __restrict__ gamma, const float* __restrict__ beta,
    float* __restrict__ out)
{
    const int r = blockIdx.x;
    const int t = threadIdx.x;
    const float* xq = q  + (size_t)r * 512;
    const float* xo = O2 + (size_t)r * 512;
    const float x0 = xq[t] + xo[t];
    const float x1 = xq[t + 256] + xo[t + 256];
    float s  = x0 + x1;
    float ss = x0 * x0 + x1 * x1;
#pragma unroll
    for (int off = 1; off < 64; off <<= 1) {
        s  += __shfl_xor(s, off);
        ss += __shfl_xor(ss, off);
    }
    __shared__ float ssum[4], ssq[4];
    const int w = t >> 6;
    if ((t & 63) == 0) { ssum[w] = s; ssq[w] = ss; }
    __syncthreads();
    const float S4 = ssum[0] + ssum[1] + ssum[2] + ssum[3];
    const float Q4 = ssq[0] + ssq[1] + ssq[2] + ssq[3];
    const float mu   = S4 * (1.0f / 512.0f);
    const float var  = Q4 * (1.0f / 512.0f) - mu * mu;
    const float rstd = rsqrtf(var + 1e-5f);
    out[(size_t)r * 512 + t]       = (x0 - mu) * rstd * gamma[t] + beta[t];
    out[(size_t)r * 512 + t + 256] = (x1 - mu) * rstd * gamma[t + 256] + beta[t + 256];
}

// =====================================================================
extern "C" void kernel_launch(void* const* d_in, const int* in_sizes, int n_in,
                              void* d_out, int out_size, void* d_ws, size_t ws_size,
                              hipStream_t stream)
{
    (void)in_sizes; (void)n_in; (void)out_size; (void)ws_size;
    const float* q    = (const float*)d_in[0];
    const float* k    = (const float*)d_in[1];
    const float* v    = (const float*)d_in[2];
    const float* mask = (const float*)d_in[3];
    const float* Wq   = (const float*)d_in[4];
    const float* bq   = (const float*)d_in[5];
    const float* Wk   = (const float*)d_in[6];
    const float* bk   = (const float*)d_in[7];
    const float* Wv   = (const float*)d_in[8];
    const float* bv   = (const float*)d_in[9];
    const float* Wo   = (const float*)d_in[10];
    const float* bo   = (const float*)d_in[11];
    const float* gamma = (const float*)d_in[12];
    const float* beta  = (const float*)d_in[13];
    float* out = (float*)d_out;

    const size_t NTOK = (size_t)Bc * Sc;          // 8192
    unsigned short* Qp = (unsigned short*)d_ws;   // bf16 [B,H,S,DK]
    unsigned short* Kp = Qp + NTOK * 512;
    unsigned short* Vp = Kp + NTOK * 512;
    unsigned short* Ap = Vp + NTOK * 512;         // bf16 [B,S,512]
    float* O2 = (float*)(Ap + NTOK * 512);        // fp32 [B,S,512]

    qkv_proj<<<dim3(128, 8, 3), 256, 0, stream>>>(q, k, v, Wq, Wk, Wv, bq, bk, bv, Qp, Kp, Vp);
    attn_kernel<<<dim3(Hc, Sc / 64, Bc), 256, 0, stream>>>(Qp, Kp, Vp, mask, Ap);
    out_proj<<<dim3(128, 8), 256, 0, stream>>>(Ap, Wo, bo, O2);
    ln_kernel<<<dim3((int)NTOK), 256, 0, stream>>>(q, O2, gamma, beta, out);
}

// Round 2
// 378.010 us; speedup vs baseline: 1.2579x; 1.2579x over previous
//
#include <hip/hip_runtime.h>

typedef __attribute__((ext_vector_type(8))) short s16x8;   // 8 bf16 (4 VGPRs)
typedef __attribute__((ext_vector_type(4))) float f32x4;   // 4 fp32 acc

__device__ __forceinline__ unsigned short f2bf(float f){
  union { float f; unsigned u; } v; v.f = f;
  return (unsigned short)((v.u + 0x7FFFu + ((v.u>>16)&1u))>>16);
}

#if __has_builtin(__builtin_amdgcn_cvt_pk_bf16_f32)
__device__ __forceinline__ unsigned pkbf(float a, float b){
  typedef __attribute__((ext_vector_type(2))) __bf16 bf16x2;
  union { bf16x2 v; unsigned u; } c;
  c.v = __builtin_amdgcn_cvt_pk_bf16_f32(a, b);
  return c.u;
}
#else
__device__ __forceinline__ unsigned pkbf(float a, float b){
  return (unsigned)f2bf(a) | ((unsigned)f2bf(b)<<16);
}
#endif

// =====================================================================
// Weight transpose+convert: Wt[n][k] = bf16(W[k][n]).  grid (8,8,4).
// =====================================================================
__global__ __launch_bounds__(256) void convert_wT(
    const float* __restrict__ W0, const float* __restrict__ W1,
    const float* __restrict__ W2, const float* __restrict__ W3,
    unsigned short* __restrict__ T0, unsigned short* __restrict__ T1,
    unsigned short* __restrict__ T2, unsigned short* __restrict__ T3)
{
  __shared__ float Ts[64][65];
  const int z = blockIdx.z;
  const float* W = (z==0)?W0:(z==1)?W1:(z==2)?W2:W3;
  unsigned short* Wt = (z==0)?T0:(z==1)?T1:(z==2)?T2:T3;
  const int t = threadIdx.x;
  const int k0 = blockIdx.x*64, n0 = blockIdx.y*64;
  {
    const int r = t>>4, c = (t&15)*4;
#pragma unroll
    for (int rr=0; rr<4; ++rr){
      const float4 w4 = *(const float4*)&W[(size_t)(k0 + r + rr*16)*512 + n0 + c];
      Ts[r+rr*16][c]   = w4.x; Ts[r+rr*16][c+1] = w4.y;
      Ts[r+rr*16][c+2] = w4.z; Ts[r+rr*16][c+3] = w4.w;
    }
  }
  __syncthreads();
  const int n = t>>2, kc = (t&3)*16;
  unsigned o[8];
#pragma unroll
  for (int i=0;i<16;i+=2) o[i>>1] = pkbf(Ts[kc+i][n], Ts[kc+i+1][n]);
  *(uint4*)&Wt[(size_t)(n0+n)*512 + k0 + kc]     = *(uint4*)&o[0];
  *(uint4*)&Wt[(size_t)(n0+n)*512 + k0 + kc + 8] = *(uint4*)&o[4];
}

// =====================================================================
// GEMM 128x128, BK=32, double-buffered, XOR-swizzled LDS.
// ZMODE 0: qkv projections (fp32 A, z=blockIdx.z picks q/k/v)
//   z0 -> Qp bf16 [B,H,S,64] scaled 1/8; z1 -> Kp; z2 -> Vtg bf16 [B,H,64,S]
// ZMODE 1: out projection (bf16 A=Ap) -> Of fp32 [8192][512]
// =====================================================================
template<int ZMODE>
__global__ __launch_bounds__(256) void gemm128(
    const float* __restrict__ Af0, const float* __restrict__ Af1, const float* __restrict__ Af2,
    const unsigned short* __restrict__ Ab,
    const unsigned short* __restrict__ Wt0, const unsigned short* __restrict__ Wt1, const unsigned short* __restrict__ Wt2,
    const float* __restrict__ bias0, const float* __restrict__ bias1, const float* __restrict__ bias2,
    unsigned short* __restrict__ Oq, unsigned short* __restrict__ Ok, unsigned short* __restrict__ Ov,
    float* __restrict__ Of)
{
  __shared__ unsigned short As[2][128*32];
  __shared__ unsigned short Bs[2][128*32];
  const int t = threadIdx.x;
  const int lane = t & 63;
  const int w = t >> 6;
  const int l16 = lane & 15;
  const int quad = lane >> 4;
  const int wm = w & 1, wn = w >> 1;
  const int bm = blockIdx.x, bn = blockIdx.y;
  const int z = (ZMODE==0) ? (int)blockIdx.z : 3;
  const float* Af = (ZMODE==0) ? ((z==0)?Af0:(z==1)?Af1:Af2) : nullptr;
  const unsigned short* Wt = (ZMODE==0) ? ((z==0)?Wt0:(z==1)?Wt1:Wt2) : Wt0;
  const float* bias = (ZMODE==0) ? ((z==0)?bias0:(z==1)?bias1:bias2) : bias0;

  const int arow = t>>1;       // 0..127
  const int ahalf = t&1;

  f32x4 acc[4][4];
#pragma unroll
  for(int i=0;i<4;i++)
#pragma unroll
    for(int j=0;j<4;j++) acc[i][j] = (f32x4){0.f,0.f,0.f,0.f};

  float4 fa[4];
  uint4 ab[2], breg[2];

  // ---- prologue: load+write tile 0 ----
  {
    if (ZMODE==0){
      const size_t abase = (size_t)(bm*128 + arow)*512 + ahalf*16;
#pragma unroll
      for (int ff=0; ff<4; ++ff) fa[ff] = *(const float4*)&Af[abase + ff*4];
    } else {
      const size_t abase = (size_t)(bm*128 + arow)*512;
#pragma unroll
      for (int j=0;j<2;++j) ab[j] = *(const uint4*)&Ab[abase + (ahalf*2 + j)*8];
    }
    const size_t bbase = (size_t)(bn*128 + arow)*512;
#pragma unroll
    for (int j=0;j<2;++j) breg[j] = *(const uint4*)&Wt[bbase + (ahalf*2 + j)*8];

    if (ZMODE==0){
#pragma unroll
      for (int j=0;j<2;++j){
        uint4 u; const float4 x = fa[j*2], y = fa[j*2+1];
        u.x = pkbf(x.x,x.y); u.y = pkbf(x.z,x.w); u.z = pkbf(y.x,y.y); u.w = pkbf(y.z,y.w);
        const int cb = ahalf*2 + j;
        *(uint4*)&As[0][arow*32 + ((cb ^ (arow&3))*8)] = u;
      }
    } else {
#pragma unroll
      for (int j=0;j<2;++j){
        const int cb = ahalf*2 + j;
        *(uint4*)&As[0][arow*32 + ((cb ^ (arow&3))*8)] = ab[j];
      }
    }
#pragma unroll
    for (int j=0;j<2;++j){
      const int cb = ahalf*2 + j;
      *(uint4*)&Bs[0][arow*32 + ((cb ^ (arow&3))*8)] = breg[j];
    }
  }

#pragma unroll 2
  for (int kt=0; kt<16; ++kt){
    const int cur = kt&1;
    if (kt<15){
      const int k0 = (kt+1)*32;
      if (ZMODE==0){
        const size_t abase = (size_t)(bm*128 + arow)*512 + k0 + ahalf*16;
#pragma unroll
        for (int ff=0; ff<4; ++ff) fa[ff] = *(const float4*)&Af[abase + ff*4];
      } else {
        const size_t abase = (size_t)(bm*128 + arow)*512 + k0;
#pragma unroll
        for (int j=0;j<2;++j) ab[j] = *(const uint4*)&Ab[abase + (ahalf*2 + j)*8];
      }
      const size_t bbase = (size_t)(bn*128 + arow)*512 + k0;
#pragma unroll
      for (int j=0;j<2;++j) breg[j] = *(const uint4*)&Wt[bbase + (ahalf*2 + j)*8];
    }
    __syncthreads();
    s16x8 af[4], bf[4];
#pragma unroll
    for (int mt=0;mt<4;++mt){
      const int row = wm*64 + mt*16 + l16;
      af[mt] = *(const s16x8*)&As[cur][row*32 + ((quad ^ (row&3))*8)];
    }
#pragma unroll
    for (int nt=0;nt<4;++nt){
      const int row = wn*64 + nt*16 + l16;
      bf[nt] = *(const s16x8*)&Bs[cur][row*32 + ((quad ^ (row&3))*8)];
    }
#pragma unroll
    for (int mt=0;mt<4;++mt)
#pragma unroll
      for (int nt=0;nt<4;++nt)
        acc[mt][nt] = __builtin_amdgcn_mfma_f32_16x16x32_bf16(af[mt], bf[nt], acc[mt][nt], 0,0,0);
    if (kt<15){
      const int nxt = cur^1;
      if (ZMODE==0){
#pragma unroll
        for (int j=0;j<2;++j){
          uint4 u; const float4 x = fa[j*2], y = fa[j*2+1];
          u.x = pkbf(x.x,x.y); u.y = pkbf(x.z,x.w); u.z = pkbf(y.x,y.y); u.w = pkbf(y.z,y.w);
          const int cb = ahalf*2 + j;
          *(uint4*)&As[nxt][arow*32 + ((cb ^ (arow&3))*8)] = u;
        }
      } else {
#pragma unroll
        for (int j=0;j<2;++j){
          const int cb = ahalf*2 + j;
          *(uint4*)&As[nxt][arow*32 + ((cb ^ (arow&3))*8)] = ab[j];
        }
      }
#pragma unroll
      for (int j=0;j<2;++j){
        const int cb = ahalf*2 + j;
        *(uint4*)&Bs[nxt][arow*32 + ((cb ^ (arow&3))*8)] = breg[j];
      }
    }
  }

  // ---- epilogue ----
#pragma unroll
  for (int mt=0;mt<4;++mt){
    const int gm = bm*128 + wm*64 + mt*16 + quad*4;
    const int b_ = gm>>11, s = gm & 2047;
#pragma unroll
    for (int nt=0;nt<4;++nt){
      const int gn = bn*128 + wn*64 + nt*16 + l16;
      const float bv = bias[gn];
      if (ZMODE==1){
#pragma unroll
        for (int r=0;r<4;++r) Of[(size_t)(gm+r)*512 + gn] = acc[mt][nt][r] + bv;
      } else if (z==2){
        const int hh = gn>>6, dk = gn&63;
        uint2 uu;
        uu.x = pkbf(acc[mt][nt][0]+bv, acc[mt][nt][1]+bv);
        uu.y = pkbf(acc[mt][nt][2]+bv, acc[mt][nt][3]+bv);
        *(uint2*)&Ov[(((size_t)b_*8 + hh)*64 + dk)*2048 + s] = uu;
      } else {
        const int hh = gn>>6, dk = gn&63;
        unsigned short* Out = (z==0)?Oq:Ok;
        const float scl = (z==0)?0.125f:1.0f;
#pragma unroll
        for (int r=0;r<4;++r)
          Out[(((size_t)b_*8 + hh)*2048 + (s+r))*64 + dk] = f2bf((acc[mt][nt][r]+bv)*scl);
      }
    }
  }
}

// =====================================================================
// Attention: S^T = K Q^T formulation, per-lane q columns, no online max.
// grid (H=8, S/128=16, B=4), block 256 (4 waves x 32 q each).
// =====================================================================
__global__ __launch_bounds__(256,2) void attn_kernel(
    const unsigned short* __restrict__ Qp, const unsigned short* __restrict__ Kp,
    const unsigned short* __restrict__ Vt, const float* __restrict__ mask,
    unsigned short* __restrict__ Ap)
{
  __shared__ unsigned short Ks[2][64*64];
  __shared__ unsigned short Vs[2][64*64];
  const int t = threadIdx.x;
  const int lane = t & 63;
  const int w = t >> 6;
  const int l16 = lane & 15;
  const int quad = lane >> 4;
  const int h = blockIdx.x, qt = blockIdx.y, b = blockIdx.z;
  const int q0 = qt*128;
  const unsigned short* Qb = Qp + (((size_t)b*8 + h)*2048 + q0)*64;
  const unsigned short* Kb = Kp + ((size_t)b*8 + h)*2048*64;
  const unsigned short* Vb = Vt + ((size_t)b*8 + h)*64*2048;
  const float* mb = mask + (size_t)b*2048*2048;

  // Q fragments (pre-scaled by 1/8 in projection): B-operand, hoisted
  s16x8 qf[2][2];
#pragma unroll
  for (int tc=0;tc<2;++tc)
#pragma unroll
    for (int kk=0;kk<2;++kk)
      qf[tc][kk] = *(const s16x8*)&Qb[(size_t)(w*32 + tc*16 + l16)*64 + kk*32 + quad*8];

  const int srow = t>>2;     // 0..63
  const int scb0 = t&3;      // +4j
  uint4 kreg[2], vreg[2];
  // prologue: tile 0
#pragma unroll
  for (int j=0;j<2;++j){
    const int cb = scb0 + 4*j;
    kreg[j] = *(const uint4*)&Kb[(size_t)srow*64 + cb*8];
    vreg[j] = *(const uint4*)&Vb[(size_t)srow*2048 + cb*8];
  }
#pragma unroll
  for (int j=0;j<2;++j){
    const int cb = scb0 + 4*j;
    *(uint4*)&Ks[0][srow*64 + ((cb ^ (srow&7))*8)] = kreg[j];
    *(uint4*)&Vs[0][srow*64 + ((cb ^ (srow&7))*8)] = vreg[j];
  }

  f32x4 o_acc[2][4];
#pragma unroll
  for(int tc=0;tc<2;++tc)
#pragma unroll
    for(int nt=0;nt<4;++nt) o_acc[tc][nt]=(f32x4){0.f,0.f,0.f,0.f};
  float l_run[2] = {0.f, 0.f};

  union U8 { unsigned u[4]; s16x8 v; };

#pragma unroll 2
  for (int kt=0; kt<32; ++kt){
    const int cur = kt&1;
    if (kt<31){
      const int kb2 = (kt+1)*64;
#pragma unroll
      for (int j=0;j<2;++j){
        const int cb = scb0 + 4*j;
        kreg[j] = *(const uint4*)&Kb[(size_t)(kb2+srow)*64 + cb*8];
        vreg[j] = *(const uint4*)&Vb[(size_t)srow*2048 + kb2 + cb*8];
      }
    }
    const int kbase = kt*64;
    float4 mr[2][4];
#pragma unroll
    for (int tc=0;tc<2;++tc){
      const int gq = q0 + w*32 + tc*16 + l16;
      const float* mrow = mb + (size_t)gq*2048 + kbase + quad*4;
#pragma unroll
      for (int nt=0;nt<4;++nt) mr[tc][nt] = *(const float4*)&mrow[nt*16];
    }
    __syncthreads();
    // S^T = K Q^T : lane l16 holds one q column per tile-col
    f32x4 sc[2][4];
#pragma unroll
    for(int tc=0;tc<2;++tc)
#pragma unroll
      for(int nt=0;nt<4;++nt) sc[tc][nt]=(f32x4){0.f,0.f,0.f,0.f};
#pragma unroll
    for (int nt=0;nt<4;++nt){
      const int row = nt*16 + l16;
      const s16x8 kf0 = *(const s16x8*)&Ks[cur][row*64 + (((quad)   ^ (l16&7))*8)];
      const s16x8 kf1 = *(const s16x8*)&Ks[cur][row*64 + (((4+quad) ^ (l16&7))*8)];
#pragma unroll
      for (int tc=0;tc<2;++tc){
        sc[tc][nt] = __builtin_amdgcn_mfma_f32_16x16x32_bf16(kf0, qf[tc][0], sc[tc][nt],0,0,0);
        sc[tc][nt] = __builtin_amdgcn_mfma_f32_16x16x32_bf16(kf1, qf[tc][1], sc[tc][nt],0,0,0);
      }
    }
    // masked threshold softmax (no running max: exp(-10000)=0) + P fragments
    U8 pu[2][2];
#pragma unroll
    for (int tc=0;tc<2;++tc){
      unsigned pk[8];
      float rs = 0.f;
#pragma unroll
      for (int nt=0;nt<4;++nt){
        const float m0 = mr[tc][nt].x, m1 = mr[tc][nt].y, m2 = mr[tc][nt].z, m3 = mr[tc][nt].w;
        float x0 = sc[tc][nt][0]*m0, x1 = sc[tc][nt][1]*m1, x2 = sc[tc][nt][2]*m2, x3 = sc[tc][nt][3]*m3;
        x0 = (x0>0.f)?x0:-10000.f; x1 = (x1>0.f)?x1:-10000.f;
        x2 = (x2>0.f)?x2:-10000.f; x3 = (x3>0.f)?x3:-10000.f;
        const float e0 = __expf(x0), e1 = __expf(x1), e2 = __expf(x2), e3 = __expf(x3);
        rs += (e0+e1)+(e2+e3);
        pk[nt*2]   = pkbf(e0, e1);
        pk[nt*2+1] = pkbf(e2, e3);
      }
      rs += __shfl_xor(rs, 16);
      rs += __shfl_xor(rs, 32);
      l_run[tc] += rs;
      // C-layout -> A/B-frag layout: cross-quad regroup via shuffles
#pragma unroll
      for (int kk=0;kk<2;++kk)
#pragma unroll
        for (int c=0;c<4;++c){
          const int srcLane = (((quad&1)*2 + (c>>1))<<4) | l16;
          const int vA = __shfl((int)pk[kk*4 + (c&1)],     srcLane);
          const int vB = __shfl((int)pk[kk*4 + 2 + (c&1)], srcLane);
          pu[tc][kk].u[c] = (quad < 2) ? (unsigned)vA : (unsigned)vB;
        }
    }
    // O^T += V^T P^T
#pragma unroll
    for (int nt=0;nt<4;++nt){
      const int row = nt*16 + l16;
      const s16x8 vf0 = *(const s16x8*)&Vs[cur][row*64 + (((quad)   ^ (l16&7))*8)];
      const s16x8 vf1 = *(const s16x8*)&Vs[cur][row*64 + (((4+quad) ^ (l16&7))*8)];
#pragma unroll
      for (int tc=0;tc<2;++tc){
        o_acc[tc][nt] = __builtin_amdgcn_mfma_f32_16x16x32_bf16(vf0, pu[tc][0].v, o_acc[tc][nt],0,0,0);
        o_acc[tc][nt] = __builtin_amdgcn_mfma_f32_16x16x32_bf16(vf1, pu[tc][1].v, o_acc[tc][nt],0,0,0);
      }
    }
    if (kt<31){
      const int nxt = cur^1;
#pragma unroll
      for (int j=0;j<2;++j){
        const int cb = scb0 + 4*j;
        *(uint4*)&Ks[nxt][srow*64 + ((cb ^ (srow&7))*8)] = kreg[j];
        *(uint4*)&Vs[nxt][srow*64 + ((cb ^ (srow&7))*8)] = vreg[j];
      }
    }
  }
  // epilogue: divide by l, write bf16 [B,S,512]
#pragma unroll
  for (int tc=0;tc<2;++tc){
    const float inv = 1.0f / l_run[tc];
    const int gq = q0 + w*32 + tc*16 + l16;
#pragma unroll
    for (int nt=0;nt<4;++nt){
      uint2 uu;
      uu.x = pkbf(o_acc[tc][nt][0]*inv, o_acc[tc][nt][1]*inv);
      uu.y = pkbf(o_acc[tc][nt][2]*inv, o_acc[tc][nt][3]*inv);
      *(uint2*)&Ap[((size_t)b*2048 + gq)*512 + h*64 + nt*16 + quad*4] = uu;
    }
  }
}

// =====================================================================
// residual + LayerNorm. grid 8192 rows, block 256.
// =====================================================================
__global__ __launch_bounds__(256) void ln_kernel(
    const float* __restrict__ q, const float* __restrict__ O2,
    const float* __restrict__ gamma, const float* __restrict__ beta,
    float* __restrict__ out)
{
  const int r = blockIdx.x;
  const int t = threadIdx.x;
  const float* xq = q  + (size_t)r * 512;
  const float* xo = O2 + (size_t)r * 512;
  const float x0 = xq[t] + xo[t];
  const float x1 = xq[t + 256] + xo[t + 256];
  float s  = x0 + x1;
  float ss = x0*x0 + x1*x1;
#pragma unroll
  for (int off = 1; off < 64; off <<= 1) {
    s  += __shfl_xor(s, off);
    ss += __shfl_xor(ss, off);
  }
  __shared__ float ssum[4], ssq[4];
  const int w = t >> 6;
  if ((t & 63) == 0) { ssum[w] = s; ssq[w] = ss; }
  __syncthreads();
  const float S4 = ssum[0] + ssum[1] + ssum[2] + ssum[3];
  const float Q4 = ssq[0] + ssq[1] + ssq[2] + ssq[3];
  const float mu   = S4 * (1.0f / 512.0f);
  const float var  = Q4 * (1.0f / 512.0f) - mu * mu;
  const float rstd = rsqrtf(var + 1e-5f);
  out[(size_t)r*512 + t]       = (x0 - mu)*rstd*gamma[t] + beta[t];
  out[(size_t)r*512 + t + 256] = (x1 - mu)*rstd*gamma[t+256] + beta[t+256];
}

// =====================================================================
extern "C" void kernel_launch(void* const* d_in, const int* in_sizes, int n_in,
                              void* d_out, int out_size, void* d_ws, size_t ws_size,
                              hipStream_t stream)
{
  (void)in_sizes; (void)n_in; (void)out_size; (void)ws_size;
  const float* q    = (const float*)d_in[0];
  const float* k    = (const float*)d_in[1];
  const float* v    = (const float*)d_in[2];
  const float* mask = (const float*)d_in[3];
  const float* Wq   = (const float*)d_in[4];
  const float* bq   = (const float*)d_in[5];
  const float* Wk   = (const float*)d_in[6];
  const float* bk   = (const float*)d_in[7];
  const float* Wv   = (const float*)d_in[8];
  const float* bv   = (const float*)d_in[9];
  const float* Wo   = (const float*)d_in[10];
  const float* bo   = (const float*)d_in[11];
  const float* gamma = (const float*)d_in[12];
  const float* beta  = (const float*)d_in[13];
  float* out = (float*)d_out;

  const size_t NT = (size_t)8192*512;   // 4,194,304
  unsigned short* WtQ = (unsigned short*)d_ws;
  unsigned short* WtK = WtQ + 512*512;
  unsigned short* WtV = WtK + 512*512;
  unsigned short* WtO = WtV + 512*512;
  unsigned short* Qp  = WtO + 512*512;      // bf16 [B,H,S,64], pre-scaled 1/8
  unsigned short* Kp  = Qp + NT;            // bf16 [B,H,S,64]
  unsigned short* Vtg = Kp + NT;            // bf16 [B,H,64,S]  (V transposed)
  unsigned short* Ap  = Vtg + NT;           // bf16 [B,S,512]
  float* O2 = (float*)(Ap + NT);            // fp32 [8192][512]

  convert_wT<<<dim3(8,8,4), 256, 0, stream>>>(Wq, Wk, Wv, Wo, WtQ, WtK, WtV, WtO);
  gemm128<0><<<dim3(64,4,3), 256, 0, stream>>>(q, k, v, nullptr,
                                               WtQ, WtK, WtV, bq, bk, bv,
                                               Qp, Kp, Vtg, nullptr);
  attn_kernel<<<dim3(8,16,4), 256, 0, stream>>>(Qp, Kp, Vtg, mask, Ap);
  gemm128<1><<<dim3(64,4,1), 256, 0, stream>>>(nullptr, nullptr, nullptr, Ap,
                                               WtO, nullptr, nullptr, bo, nullptr, nullptr,
                                               nullptr, nullptr, nullptr, O2);
  ln_kernel<<<dim3(8192), 256, 0, stream>>>(q, O2, gamma, beta, out);
}

// Round 3
// 311.268 us; speedup vs baseline: 1.5276x; 1.2144x over previous
//
#include <hip/hip_runtime.h>
#include <stdint.h>

typedef __attribute__((ext_vector_type(8))) short s16x8;   // 8 bf16 (4 VGPRs)
typedef __attribute__((ext_vector_type(4))) float f32x4;   // 4 fp32 acc

__device__ __forceinline__ unsigned short f2bf(float f){
  union { float f; unsigned u; } v; v.f = f;
  return (unsigned short)((v.u + 0x7FFFu + ((v.u>>16)&1u))>>16);
}
__device__ __forceinline__ float bf2f(unsigned short u){
  union { unsigned u; float f; } c; c.u = ((unsigned)u)<<16; return c.f;
}
#if __has_builtin(__builtin_amdgcn_cvt_pk_bf16_f32)
__device__ __forceinline__ unsigned pkbf(float a, float b){
  typedef __attribute__((ext_vector_type(2))) __bf16 bf16x2;
  union { bf16x2 v; unsigned u; } c;
  c.v = __builtin_amdgcn_cvt_pk_bf16_f32(a, b);
  return c.u;
}
#else
__device__ __forceinline__ unsigned pkbf(float a, float b){
  return (unsigned)f2bf(a) | ((unsigned)f2bf(b)<<16);
}
#endif

// async global->LDS, 16B per lane; LDS dest = wave-uniform base + lane*16 (CK idiom)
__device__ __forceinline__ void g2l16(const void* g, void* l){
  auto* lp = reinterpret_cast<__attribute__((address_space(3))) unsigned int*>(
      reinterpret_cast<uintptr_t>(l));
  auto* gp = reinterpret_cast<const __attribute__((address_space(1))) unsigned int*>(
      reinterpret_cast<uintptr_t>(g));
  __builtin_amdgcn_global_load_lds(gp, lp, 16, 0, 0);
}

// =====================================================================
// Prep: fp32 -> bf16 streams. z=0: mask (16.7M), z=1..3: q/k/v (4.19M).
// grid (8192,1,4) x 256, 8 elems/thread.
// =====================================================================
__global__ __launch_bounds__(256) void cvt_all(
    const float* __restrict__ mask, const float* __restrict__ q,
    const float* __restrict__ k,    const float* __restrict__ v,
    unsigned short* __restrict__ mo, unsigned short* __restrict__ qo,
    unsigned short* __restrict__ ko, unsigned short* __restrict__ vo)
{
  const int z = blockIdx.z;
  const float* src = (z==0)?mask:(z==1)?q:(z==2)?k:v;
  unsigned short* dst = (z==0)?mo:(z==1)?qo:(z==2)?ko:vo;
  const int n = (z==0) ? 4*2048*2048 : 8192*512;
  const int i8 = (blockIdx.x*256 + threadIdx.x)*8;
  if (i8 < n){
    const float4 a = *(const float4*)&src[i8];
    const float4 b = *(const float4*)&src[i8+4];
    uint4 o;
    o.x = pkbf(a.x,a.y); o.y = pkbf(a.z,a.w);
    o.z = pkbf(b.x,b.y); o.w = pkbf(b.z,b.w);
    *(uint4*)&dst[i8] = o;
  }
}

// =====================================================================
// Weight transpose+convert: Wt[n][k] = bf16(W[k][n]).  grid (8,8,4).
// =====================================================================
__global__ __launch_bounds__(256) void convert_wT(
    const float* __restrict__ W0, const float* __restrict__ W1,
    const float* __restrict__ W2, const float* __restrict__ W3,
    unsigned short* __restrict__ T0, unsigned short* __restrict__ T1,
    unsigned short* __restrict__ T2, unsigned short* __restrict__ T3)
{
  __shared__ float Ts[64][65];
  const int z = blockIdx.z;
  const float* W = (z==0)?W0:(z==1)?W1:(z==2)?W2:W3;
  unsigned short* Wt = (z==0)?T0:(z==1)?T1:(z==2)?T2:T3;
  const int t = threadIdx.x;
  const int k0 = blockIdx.x*64, n0 = blockIdx.y*64;
  {
    const int r = t>>4, c = (t&15)*4;
#pragma unroll
    for (int rr=0; rr<4; ++rr){
      const float4 w4 = *(const float4*)&W[(size_t)(k0 + r + rr*16)*512 + n0 + c];
      Ts[r+rr*16][c]   = w4.x; Ts[r+rr*16][c+1] = w4.y;
      Ts[r+rr*16][c+2] = w4.z; Ts[r+rr*16][c+3] = w4.w;
    }
  }
  __syncthreads();
  const int n = t>>2, kc = (t&3)*16;
  unsigned o[8];
#pragma unroll
  for (int i=0;i<16;i+=2) o[i>>1] = pkbf(Ts[kc+i][n], Ts[kc+i+1][n]);
  *(uint4*)&Wt[(size_t)(n0+n)*512 + k0 + kc]     = *(uint4*)&o[0];
  *(uint4*)&Wt[(size_t)(n0+n)*512 + k0 + kc + 8] = *(uint4*)&o[4];
}

// =====================================================================
// m97-style GEMM: 128x128 tile, BK=64, bf16 A/B, global_load_lds staging
// with global-side XOR chunk swizzle (conflict-free frag reads).
// EPI 0 (z=0,1,2): qkv -> Qp/Kp [B,H,S,64] (Q scaled 1/8), Vtg [B,H,64,S]
// EPI 1: out-proj -> O2 bf16 [8192][512]
// =====================================================================
template<int EPI>
__global__ __launch_bounds__(256) void gemm_m97(
    const unsigned short* __restrict__ A0, const unsigned short* __restrict__ A1,
    const unsigned short* __restrict__ A2,
    const unsigned short* __restrict__ W0, const unsigned short* __restrict__ W1,
    const unsigned short* __restrict__ W2,
    const float* __restrict__ b0, const float* __restrict__ b1, const float* __restrict__ b2,
    unsigned short* __restrict__ Oq, unsigned short* __restrict__ Ok,
    unsigned short* __restrict__ Ov, unsigned short* __restrict__ Oflat)
{
  __shared__ unsigned short As[128*64];
  __shared__ unsigned short Bs[128*64];
  const int t = threadIdx.x;
  const int lane = t & 63;
  const int w = t >> 6;
  const int l16 = lane & 15;
  const int quad = lane >> 4;
  const int wm = w & 1, wn = w >> 1;
  const int bm = blockIdx.x, bn = blockIdx.y;
  const int z = (EPI==0) ? (int)blockIdx.z : 0;
  const unsigned short* A  = (z==0)?A0:(z==1)?A1:A2;
  const unsigned short* Wt = (z==0)?W0:(z==1)?W1:W2;
  const float* bias        = (z==0)?b0:(z==1)?b1:b2;

  const int Lr = lane >> 3;          // 0..7 row within 8-row group
  const int gc = (lane & 7) ^ Lr;    // global chunk (XOR swizzle)

  f32x4 acc[4][4];
#pragma unroll
  for(int i=0;i<4;i++)
#pragma unroll
    for(int j=0;j<4;j++) acc[i][j] = (f32x4){0.f,0.f,0.f,0.f};

  for (int kt=0; kt<8; ++kt){
    const int k0 = kt*64;
    // stage A and B tiles (128x64 bf16 each) via async direct-to-LDS
#pragma unroll
    for (int j=0;j<4;++j){
      const int rb = w*32 + j*8;
      g2l16(&A [(size_t)(bm*128 + rb + Lr)*512 + k0 + gc*8], &As[rb*64]);
      g2l16(&Wt[(size_t)(bn*128 + rb + Lr)*512 + k0 + gc*8], &Bs[rb*64]);
    }
    __syncthreads();   // drains vmcnt(0): staged data visible
#pragma unroll
    for (int kk=0;kk<2;++kk){
      s16x8 af[4], bfr[4];
#pragma unroll
      for (int mt=0;mt<4;++mt){
        const int row = wm*64 + mt*16 + l16;
        af[mt] = *(const s16x8*)&As[row*64 + (((kk*4+quad) ^ (row&7))*8)];
      }
#pragma unroll
      for (int nt=0;nt<4;++nt){
        const int row = wn*64 + nt*16 + l16;
        bfr[nt] = *(const s16x8*)&Bs[row*64 + (((kk*4+quad) ^ (row&7))*8)];
      }
#pragma unroll
      for (int mt=0;mt<4;++mt)
#pragma unroll
        for (int nt=0;nt<4;++nt)
          acc[mt][nt] = __builtin_amdgcn_mfma_f32_16x16x32_bf16(af[mt], bfr[nt], acc[mt][nt], 0,0,0);
    }
    __syncthreads();   // all reads done before restage
  }

  // ---- epilogue ----
#pragma unroll
  for (int mt=0;mt<4;++mt){
    const int gm = bm*128 + wm*64 + mt*16 + quad*4;
    const int b_ = gm>>11, s = gm & 2047;
#pragma unroll
    for (int nt=0;nt<4;++nt){
      const int gn = bn*128 + wn*64 + nt*16 + l16;
      const float bv = bias[gn];
      if (EPI==1){
#pragma unroll
        for (int r=0;r<4;++r)
          Oflat[(size_t)(gm+r)*512 + gn] = f2bf(acc[mt][nt][r] + bv);
      } else if (z==2){
        const int hh = gn>>6, dk = gn&63;
        uint2 uu;
        uu.x = pkbf(acc[mt][nt][0]+bv, acc[mt][nt][1]+bv);
        uu.y = pkbf(acc[mt][nt][2]+bv, acc[mt][nt][3]+bv);
        *(uint2*)&Ov[(((size_t)b_*8 + hh)*64 + dk)*2048 + s] = uu;
      } else {
        const int hh = gn>>6, dk = gn&63;
        unsigned short* Out = (z==0)?Oq:Ok;
        const float scl = (z==0)?0.125f:1.0f;
#pragma unroll
        for (int r=0;r<4;++r)
          Out[(((size_t)b_*8 + hh)*2048 + (s+r))*64 + dk] = f2bf((acc[mt][nt][r]+bv)*scl);
      }
    }
  }
}

// =====================================================================
// Attention: S^T = K Q^T, per-lane q columns, bf16 mask, no online max.
// grid (8,16,4) x 512 threads (8 waves x 16 q rows = 128-q tile).
// Double-buffered K/V via global_load_lds; ONE barrier per k-tile.
// =====================================================================
__global__ __launch_bounds__(512,4) void attn_kernel(
    const unsigned short* __restrict__ Qp, const unsigned short* __restrict__ Kp,
    const unsigned short* __restrict__ Vt, const unsigned short* __restrict__ maskb,
    unsigned short* __restrict__ Ap)
{
  __shared__ unsigned short Ks[2][64*64];
  __shared__ unsigned short Vs[2][64*64];
  const int t = threadIdx.x;
  const int lane = t & 63;
  const int w = t >> 6;              // 0..7
  const int l16 = lane & 15;
  const int quad = lane >> 4;
  const int h = blockIdx.x, qt = blockIdx.y, b = blockIdx.z;
  const int q0 = qt*128;
  const unsigned short* Qb = Qp + (((size_t)b*8 + h)*2048 + q0)*64;
  const unsigned short* Kb = Kp + ((size_t)b*8 + h)*2048*64;
  const unsigned short* Vb = Vt + ((size_t)b*8 + h)*64*2048;
  const unsigned short* mb = maskb + (size_t)b*2048*2048;

  // Q fragments (pre-scaled 1/8): B-operand, n = q = w*16+l16
  s16x8 qf[2];
#pragma unroll
  for (int kk=0;kk<2;++kk)
    qf[kk] = *(const s16x8*)&Qb[(size_t)(w*16 + l16)*64 + kk*32 + quad*8];

  const int Lr = lane >> 3;          // 0..7
  const int gc = (lane & 7) ^ Lr;    // global chunk XOR swizzle
  const int srow = w*8 + Lr;         // staging row 0..63 (wave w: rows w*8..w*8+7)

  // prologue: stage tile 0
  g2l16(&Kb[(size_t)srow*64   + gc*8], &Ks[0][w*8*64]);
  g2l16(&Vb[(size_t)srow*2048 + gc*8], &Vs[0][w*8*64]);

  f32x4 o_acc[4];
#pragma unroll
  for(int nt=0;nt<4;++nt) o_acc[nt]=(f32x4){0.f,0.f,0.f,0.f};
  float l_run = 0.f;

  union U8 { unsigned u[4]; s16x8 v; };
  const int gq = q0 + w*16 + l16;

  for (int kt=0; kt<32; ++kt){
    const int cur = kt&1;
    const int kbase = kt*64;
    __syncthreads();   // buf[cur] staged; prev reads of buf[cur^1] done

    // mask loads first (oldest vmem -> waiting for them won't drain prefetch)
    uint2 mr[4];
    {
      const unsigned short* mrow = mb + (size_t)gq*2048 + kbase + quad*4;
#pragma unroll
      for (int nt=0;nt<4;++nt) mr[nt] = *(const uint2*)&mrow[nt*16];
    }
    // prefetch next tile into buf[cur^1] (drained by NEXT iteration's barrier)
    if (kt<31){
      const int kb2 = (kt+1)*64;
      g2l16(&Kb[(size_t)(kb2+srow)*64 + gc*8],   &Ks[cur^1][w*8*64]);
      g2l16(&Vb[(size_t)srow*2048 + kb2 + gc*8], &Vs[cur^1][w*8*64]);
    }

    // S^T = K Q^T : lane l16 = one q column; rows = k
    f32x4 sc[4];
#pragma unroll
    for(int nt=0;nt<4;++nt) sc[nt]=(f32x4){0.f,0.f,0.f,0.f};
#pragma unroll
    for (int nt=0;nt<4;++nt){
      const int row = nt*16 + l16;
      const int rx = row & 7;
      const s16x8 kf0 = *(const s16x8*)&Ks[cur][row*64 + ((quad ^ rx)*8)];
      const s16x8 kf1 = *(const s16x8*)&Ks[cur][row*64 + (((4+quad) ^ rx)*8)];
      sc[nt] = __builtin_amdgcn_mfma_f32_16x16x32_bf16(kf0, qf[0], sc[nt],0,0,0);
      sc[nt] = __builtin_amdgcn_mfma_f32_16x16x32_bf16(kf1, qf[1], sc[nt],0,0,0);
    }
    // mask*threshold softmax (no running max: exp(-10000)=0)
    unsigned pk[8];
    float rs = 0.f;
#pragma unroll
    for (int nt=0;nt<4;++nt){
      const float m0 = bf2f((unsigned short)(mr[nt].x & 0xffffu));
      const float m1 = bf2f((unsigned short)(mr[nt].x >> 16));
      const float m2 = bf2f((unsigned short)(mr[nt].y & 0xffffu));
      const float m3 = bf2f((unsigned short)(mr[nt].y >> 16));
      float x0 = sc[nt][0]*m0, x1 = sc[nt][1]*m1, x2 = sc[nt][2]*m2, x3 = sc[nt][3]*m3;
      x0 = (x0>0.f)?x0:-10000.f; x1 = (x1>0.f)?x1:-10000.f;
      x2 = (x2>0.f)?x2:-10000.f; x3 = (x3>0.f)?x3:-10000.f;
      const float e0 = __expf(x0), e1 = __expf(x1), e2 = __expf(x2), e3 = __expf(x3);
      rs += (e0+e1)+(e2+e3);
      pk[nt*2]   = pkbf(e0, e1);
      pk[nt*2+1] = pkbf(e2, e3);
    }
    rs += __shfl_xor(rs, 16);
    rs += __shfl_xor(rs, 32);
    l_run += rs;
    // C-layout -> B-frag layout: cross-quad regroup via shuffles (proven r2)
    U8 pu[2];
#pragma unroll
    for (int kk=0;kk<2;++kk)
#pragma unroll
      for (int c=0;c<4;++c){
        const int srcLane = (((quad&1)*2 + (c>>1))<<4) | l16;
        const int vA = __shfl((int)pk[kk*4 + (c&1)],     srcLane);
        const int vB = __shfl((int)pk[kk*4 + 2 + (c&1)], srcLane);
        pu[kk].u[c] = (quad < 2) ? (unsigned)vA : (unsigned)vB;
      }
    // O^T += V^T P^T
#pragma unroll
    for (int nt=0;nt<4;++nt){
      const int row = nt*16 + l16;
      const int rx = row & 7;
      const s16x8 vf0 = *(const s16x8*)&Vs[cur][row*64 + ((quad ^ rx)*8)];
      const s16x8 vf1 = *(const s16x8*)&Vs[cur][row*64 + (((4+quad) ^ rx)*8)];
      o_acc[nt] = __builtin_amdgcn_mfma_f32_16x16x32_bf16(vf0, pu[0].v, o_acc[nt],0,0,0);
      o_acc[nt] = __builtin_amdgcn_mfma_f32_16x16x32_bf16(vf1, pu[1].v, o_acc[nt],0,0,0);
    }
  }
  // epilogue: /l, write bf16 [B,S,512]
  {
    const float inv = 1.0f / l_run;
#pragma unroll
    for (int nt=0;nt<4;++nt){
      uint2 uu;
      uu.x = pkbf(o_acc[nt][0]*inv, o_acc[nt][1]*inv);
      uu.y = pkbf(o_acc[nt][2]*inv, o_acc[nt][3]*inv);
      *(uint2*)&Ap[((size_t)b*2048 + gq)*512 + h*64 + nt*16 + quad*4] = uu;
    }
  }
}

// =====================================================================
// residual + LayerNorm (bf16 projected output). grid 8192 x 256.
// =====================================================================
__global__ __launch_bounds__(256) void ln_kernel(
    const float* __restrict__ q, const unsigned short* __restrict__ O2,
    const float* __restrict__ gamma, const float* __restrict__ beta,
    float* __restrict__ out)
{
  const int r = blockIdx.x;
  const int t = threadIdx.x;
  const float* xq = q + (size_t)r * 512;
  const unsigned short* xo = O2 + (size_t)r * 512;
  const float x0 = xq[t]       + bf2f(xo[t]);
  const float x1 = xq[t + 256] + bf2f(xo[t + 256]);
  float s  = x0 + x1;
  float ss = x0*x0 + x1*x1;
#pragma unroll
  for (int off = 1; off < 64; off <<= 1) {
    s  += __shfl_xor(s, off);
    ss += __shfl_xor(ss, off);
  }
  __shared__ float ssum[4], ssq[4];
  const int w = t >> 6;
  if ((t & 63) == 0) { ssum[w] = s; ssq[w] = ss; }
  __syncthreads();
  const float S4 = ssum[0] + ssum[1] + ssum[2] + ssum[3];
  const float Q4 = ssq[0] + ssq[1] + ssq[2] + ssq[3];
  const float mu   = S4 * (1.0f / 512.0f);
  const float var  = Q4 * (1.0f / 512.0f) - mu * mu;
  const float rstd = rsqrtf(var + 1e-5f);
  out[(size_t)r*512 + t]       = (x0 - mu)*rstd*gamma[t] + beta[t];
  out[(size_t)r*512 + t + 256] = (x1 - mu)*rstd*gamma[t+256] + beta[t+256];
}

// =====================================================================
extern "C" void kernel_launch(void* const* d_in, const int* in_sizes, int n_in,
                              void* d_out, int out_size, void* d_ws, size_t ws_size,
                              hipStream_t stream)
{
  (void)in_sizes; (void)n_in; (void)out_size; (void)ws_size;
  const float* q    = (const float*)d_in[0];
  const float* k    = (const float*)d_in[1];
  const float* v    = (const float*)d_in[2];
  const float* mask = (const float*)d_in[3];
  const float* Wq   = (const float*)d_in[4];
  const float* bq   = (const float*)d_in[5];
  const float* Wk   = (const float*)d_in[6];
  const float* bk   = (const float*)d_in[7];
  const float* Wv   = (const float*)d_in[8];
  const float* bv   = (const float*)d_in[9];
  const float* Wo   = (const float*)d_in[10];
  const float* bo   = (const float*)d_in[11];
  const float* gamma = (const float*)d_in[12];
  const float* beta  = (const float*)d_in[13];
  float* out = (float*)d_out;

  const size_t NT = (size_t)8192*512;           // 4,194,304
  unsigned short* WtQ  = (unsigned short*)d_ws; // 4 x 512x512 bf16
  unsigned short* WtK  = WtQ + 512*512;
  unsigned short* WtV  = WtK + 512*512;
  unsigned short* WtO  = WtV + 512*512;
  unsigned short* Mb   = WtO + 512*512;         // bf16 mask [B,S,S]
  unsigned short* qb   = Mb + (size_t)4*2048*2048;
  unsigned short* kb   = qb + NT;               // bf16 inputs [8192][512]
  unsigned short* vb   = kb + NT;
  unsigned short* Qp   = vb + NT;               // bf16 [B,H,S,64], pre-scaled 1/8
  unsigned short* Kp   = Qp + NT;               // bf16 [B,H,S,64]
  unsigned short* Vtg  = Kp + NT;               // bf16 [B,H,64,S]
  unsigned short* Ap   = Vtg + NT;              // bf16 [B,S,512]
  unsigned short* O2b  = Ap + NT;               // bf16 [8192][512]

  cvt_all<<<dim3(8192,1,4), 256, 0, stream>>>(mask, q, k, v, Mb, qb, kb, vb);
  convert_wT<<<dim3(8,8,4), 256, 0, stream>>>(Wq, Wk, Wv, Wo, WtQ, WtK, WtV, WtO);
  gemm_m97<0><<<dim3(64,4,3), 256, 0, stream>>>(qb, kb, vb, WtQ, WtK, WtV,
                                                bq, bk, bv, Qp, Kp, Vtg, nullptr);
  attn_kernel<<<dim3(8,16,4), 512, 0, stream>>>(Qp, Kp, Vtg, Mb, Ap);
  gemm_m97<1><<<dim3(64,4,1), 256, 0, stream>>>(Ap, nullptr, nullptr, WtO, nullptr, nullptr,
                                                bo, nullptr, nullptr,
                                                nullptr, nullptr, nullptr, O2b);
  ln_kernel<<<dim3(8192), 256, 0, stream>>>(q, O2b, gamma, beta, out);
}